// Round 1
// baseline (14146.190 us; speedup 1.0000x reference)
//
#include <hip/hip_runtime.h>
#include <math.h>

#define B_   32
#define TI_  128
#define TO_  64
#define E_   256
#define H_   512
#define A_   512
#define VO_  32000
#define G3_  1536   // 3H
#define D2H_ 1024   // 2H

// ---------------- small utility kernels ----------------

__global__ __launch_bounds__(256) void k_zero(float* __restrict__ p, int n) {
  int i = blockIdx.x * 256 + threadIdx.x;
  if (i < n) p[i] = 0.f;
}

__global__ __launch_bounds__(256) void k_gather_x(const int* __restrict__ inp,
                                                  const float* __restrict__ emb,
                                                  float* __restrict__ x) {
  int idx = blockIdx.x * 256 + threadIdx.x;      // float4 index
  int total = B_ * TI_ * E_ / 4;
  if (idx >= total) return;
  int row = idx / (E_ / 4);
  int e4  = idx % (E_ / 4);
  int tok = inp[row];
  ((float4*)x)[idx] = ((const float4*)emb)[(size_t)tok * (E_ / 4) + e4];
}

__global__ __launch_bounds__(256) void k_gather_xe(const int* __restrict__ outidx,
                                                   const float* __restrict__ emb,
                                                   float* __restrict__ xe) {
  int idx = blockIdx.x * 256 + threadIdx.x;
  int total = 63 * B_ * E_ / 4;
  if (idx >= total) return;
  int row = idx / (E_ / 4);      // = i*32 + b
  int e4  = idx % (E_ / 4);
  int i = row / B_, b = row % B_;
  int tok = outidx[b * TO_ + i];
  ((float4*)xe)[idx] = ((const float4*)emb)[(size_t)tok * (E_ / 4) + e4];
}

__global__ __launch_bounds__(256) void k_first(float* __restrict__ dout) {
  int idx = blockIdx.x * 256 + threadIdx.x;
  if (idx >= B_ * VO_) return;
  int b = idx / VO_, v = idx % VO_;
  // log(one_hot(BOS=1) + 1e-9) in f32
  dout[(size_t)b * TO_ * VO_ + v] = (v == 1) ? 0.f : -20.72326583694641f;
}

// ---------------- generic f32 GEMM: C[M,N] = A[M,lda-K] @ W[N,ldw]^T + bias ----
// MODE 0: C[m*N+n];  MODE 1: logits -> d_out[((m%32)*TO + m/32 + 1)*VO + n]

template <int MODE>
__global__ __launch_bounds__(256) void k_gemm128(
    const float* __restrict__ A, int lda,
    const float* __restrict__ W, int ldw,
    const float* __restrict__ bias,
    float* __restrict__ C, int M, int N, int K) {
  __shared__ float As[32][132];
  __shared__ float Bs[32][132];
  const int tid = threadIdx.x;
  const int m0 = blockIdx.y * 128, n0 = blockIdx.x * 128;
  const int tx = tid & 15, ty = tid >> 4;
  float acc[8][8];
#pragma unroll
  for (int i = 0; i < 8; ++i)
#pragma unroll
    for (int j = 0; j < 8; ++j) acc[i][j] = 0.f;

  for (int k0 = 0; k0 < K; k0 += 32) {
#pragma unroll
    for (int i = 0; i < 16; ++i) {
      int idx = tid + i * 256;
      int kk = idx & 31, mm = idx >> 5;
      int m = m0 + mm;
      As[kk][mm] = (m < M) ? A[(size_t)m * lda + k0 + kk] : 0.f;
      Bs[kk][mm] = W[(size_t)(n0 + mm) * ldw + k0 + kk];
    }
    __syncthreads();
#pragma unroll
    for (int kk = 0; kk < 32; ++kk) {
      float4 a0 = *(const float4*)&As[kk][ty * 8];
      float4 a1 = *(const float4*)&As[kk][ty * 8 + 4];
      float4 b0 = *(const float4*)&Bs[kk][tx * 8];
      float4 b1 = *(const float4*)&Bs[kk][tx * 8 + 4];
      float av[8] = {a0.x, a0.y, a0.z, a0.w, a1.x, a1.y, a1.z, a1.w};
      float bv[8] = {b0.x, b0.y, b0.z, b0.w, b1.x, b1.y, b1.z, b1.w};
#pragma unroll
      for (int i = 0; i < 8; ++i)
#pragma unroll
        for (int j = 0; j < 8; ++j) acc[i][j] = fmaf(av[i], bv[j], acc[i][j]);
    }
    __syncthreads();
  }

#pragma unroll
  for (int i = 0; i < 8; ++i) {
    int m = m0 + ty * 8 + i;
    if (m >= M) continue;
#pragma unroll
    for (int j = 0; j < 8; ++j) {
      int n = n0 + tx * 8 + j;
      float vv = acc[i][j] + bias[n];
      if (MODE == 1) {
        int b = m & 31, st = m >> 5;
        C[((size_t)b * TO_ + st + 1) * VO_ + n] = vv;
      } else {
        C[(size_t)m * N + n] = vv;
      }
    }
  }
}

// ---------------- encoder step (both directions, fused GEMM+gates) ----------
// grid 128 blocks: blocks 0..63 forward, 64..127 backward; each block owns 8 h-cols.
// 256 threads: m = tid&31 (batch), c = tid>>5 (col within slice).

__global__ __launch_bounds__(256) void k_enc_step(
    const float* __restrict__ hf_in, float* __restrict__ hf_out,
    const float* __restrict__ hb_in, float* __restrict__ hb_out,
    const float* __restrict__ xp_f, const float* __restrict__ xp_b,
    const float* __restrict__ Whh_f, const float* __restrict__ bhh_f,
    const float* __restrict__ Whh_b, const float* __restrict__ bhh_b,
    float* __restrict__ enc, int t) {
  __shared__ float hs[32 * 516];   // padded stride 516 to dodge bank conflicts
  const int bid = blockIdx.x;
  const int dir = bid >> 6;
  const int slice = bid & 63;
  const float* h_in  = dir ? hb_in : hf_in;
  float*       h_out = dir ? hb_out : hf_out;
  const float* xp    = dir ? xp_b : xp_f;
  const float* Whh   = dir ? Whh_b : Whh_f;
  const float* bhh   = dir ? bhh_b : bhh_f;
  const int tt = dir ? (TI_ - 1 - t) : t;
  const int tid = threadIdx.x;

  // stage h [32][512] into LDS
#pragma unroll
  for (int i = 0; i < 16; ++i) {
    int idx4 = tid + i * 256;
    int flat = idx4 * 4;
    int mm = flat >> 9, kk = flat & 511;
    *(float4*)&hs[mm * 516 + kk] = *(const float4*)(h_in + (size_t)mm * H_ + kk);
  }
  __syncthreads();

  const int m = tid & 31, c = tid >> 5;
  const int col = slice * 8 + c;
  const float* hrow = hs + m * 516;
  const float4* wr = (const float4*)(Whh + (size_t)col * H_);
  const float4* wz = (const float4*)(Whh + (size_t)(H_ + col) * H_);
  const float4* wn = (const float4*)(Whh + (size_t)(2 * H_ + col) * H_);
  float accr = 0.f, accz = 0.f, accn = 0.f;
#pragma unroll 4
  for (int k4 = 0; k4 < H_ / 4; ++k4) {
    float4 h4 = *(const float4*)(hrow + k4 * 4);
    float4 r = wr[k4], z = wz[k4], n = wn[k4];
    accr = fmaf(h4.x, r.x, fmaf(h4.y, r.y, fmaf(h4.z, r.z, fmaf(h4.w, r.w, accr))));
    accz = fmaf(h4.x, z.x, fmaf(h4.y, z.y, fmaf(h4.z, z.z, fmaf(h4.w, z.w, accz))));
    accn = fmaf(h4.x, n.x, fmaf(h4.y, n.y, fmaf(h4.z, n.z, fmaf(h4.w, n.w, accn))));
  }
  size_t xoff = ((size_t)m * TI_ + tt) * G3_ + col;
  float xr = xp[xoff], xz = xp[xoff + 512], xn = xp[xoff + 1024];
  float hr = accr + bhh[col];
  float hz = accz + bhh[512 + col];
  float hn = accn + bhh[1024 + col];
  float r = 1.f / (1.f + expf(-(xr + hr)));
  float z = 1.f / (1.f + expf(-(xz + hz)));
  float nn = tanhf(xn + r * hn);
  float hold = hrow[col];
  float hnew = (1.f - z) * nn + z * hold;
  h_out[m * H_ + col] = hnew;
  enc[((size_t)m * TI_ + tt) * D2H_ + dir * H_ + col] = hnew;
}

// ---------------- decoder recurrence step (xg_a + hg + gates) ----------------
// grid 64 blocks (8 h-cols each), 256 threads (m = tid&31, c = tid>>5).

__global__ __launch_bounds__(256) void k_dec_step(
    const float* __restrict__ h_in, float* __restrict__ h_out,
    const float* __restrict__ a_in, const float* __restrict__ XE,
    const float* __restrict__ Wih, const float* __restrict__ Whh,
    const float* __restrict__ bhh,
    float* __restrict__ HA, int step) {
  __shared__ float buf[32 * 516];
  const int tid = threadIdx.x;
  const int m = tid & 31, c = tid >> 5;
  const int col = blockIdx.x * 8 + c;
  const float* hrow = buf + m * 516;
  float axr = 0.f, axz = 0.f, axn = 0.f, ahr = 0.f, ahz = 0.f, ahn = 0.f;

  // ---- phase 1: a[:, 0:512] ----
#pragma unroll
  for (int i = 0; i < 16; ++i) {
    int idx4 = tid + i * 256;
    int flat = idx4 * 4;
    int mm = flat >> 9, kk = flat & 511;
    *(float4*)&buf[mm * 516 + kk] = *(const float4*)(a_in + (size_t)mm * D2H_ + kk);
  }
  __syncthreads();
  {
    const float4* wr = (const float4*)(Wih + (size_t)col * 1280 + 256);
    const float4* wz = (const float4*)(Wih + (size_t)(512 + col) * 1280 + 256);
    const float4* wn = (const float4*)(Wih + (size_t)(1024 + col) * 1280 + 256);
#pragma unroll 4
    for (int k4 = 0; k4 < 128; ++k4) {
      float4 h4 = *(const float4*)(hrow + k4 * 4);
      float4 r = wr[k4], z = wz[k4], n = wn[k4];
      axr = fmaf(h4.x, r.x, fmaf(h4.y, r.y, fmaf(h4.z, r.z, fmaf(h4.w, r.w, axr))));
      axz = fmaf(h4.x, z.x, fmaf(h4.y, z.y, fmaf(h4.z, z.z, fmaf(h4.w, z.w, axz))));
      axn = fmaf(h4.x, n.x, fmaf(h4.y, n.y, fmaf(h4.z, n.z, fmaf(h4.w, n.w, axn))));
    }
  }
  __syncthreads();

  // ---- phase 2: a[:, 512:1024] ----
#pragma unroll
  for (int i = 0; i < 16; ++i) {
    int idx4 = tid + i * 256;
    int flat = idx4 * 4;
    int mm = flat >> 9, kk = flat & 511;
    *(float4*)&buf[mm * 516 + kk] = *(const float4*)(a_in + (size_t)mm * D2H_ + 512 + kk);
  }
  __syncthreads();
  {
    const float4* wr = (const float4*)(Wih + (size_t)col * 1280 + 768);
    const float4* wz = (const float4*)(Wih + (size_t)(512 + col) * 1280 + 768);
    const float4* wn = (const float4*)(Wih + (size_t)(1024 + col) * 1280 + 768);
#pragma unroll 4
    for (int k4 = 0; k4 < 128; ++k4) {
      float4 h4 = *(const float4*)(hrow + k4 * 4);
      float4 r = wr[k4], z = wz[k4], n = wn[k4];
      axr = fmaf(h4.x, r.x, fmaf(h4.y, r.y, fmaf(h4.z, r.z, fmaf(h4.w, r.w, axr))));
      axz = fmaf(h4.x, z.x, fmaf(h4.y, z.y, fmaf(h4.z, z.z, fmaf(h4.w, z.w, axz))));
      axn = fmaf(h4.x, n.x, fmaf(h4.y, n.y, fmaf(h4.z, n.z, fmaf(h4.w, n.w, axn))));
    }
  }
  __syncthreads();

  // ---- phase 3: h ----
#pragma unroll
  for (int i = 0; i < 16; ++i) {
    int idx4 = tid + i * 256;
    int flat = idx4 * 4;
    int mm = flat >> 9, kk = flat & 511;
    *(float4*)&buf[mm * 516 + kk] = *(const float4*)(h_in + (size_t)mm * H_ + kk);
  }
  __syncthreads();
  {
    const float4* wr = (const float4*)(Whh + (size_t)col * H_);
    const float4* wz = (const float4*)(Whh + (size_t)(512 + col) * H_);
    const float4* wn = (const float4*)(Whh + (size_t)(1024 + col) * H_);
#pragma unroll 4
    for (int k4 = 0; k4 < 128; ++k4) {
      float4 h4 = *(const float4*)(hrow + k4 * 4);
      float4 r = wr[k4], z = wz[k4], n = wn[k4];
      ahr = fmaf(h4.x, r.x, fmaf(h4.y, r.y, fmaf(h4.z, r.z, fmaf(h4.w, r.w, ahr))));
      ahz = fmaf(h4.x, z.x, fmaf(h4.y, z.y, fmaf(h4.z, z.z, fmaf(h4.w, z.w, ahz))));
      ahn = fmaf(h4.x, n.x, fmaf(h4.y, n.y, fmaf(h4.z, n.z, fmaf(h4.w, n.w, ahn))));
    }
  }

  size_t xrow = ((size_t)step * B_ + m) * G3_;
  float xr = XE[xrow + col] + axr;
  float xz = XE[xrow + 512 + col] + axz;
  float xn = XE[xrow + 1024 + col] + axn;
  float hr = ahr + bhh[col];
  float hz = ahz + bhh[512 + col];
  float hn = ahn + bhh[1024 + col];
  float r = 1.f / (1.f + expf(-(xr + hr)));
  float z = 1.f / (1.f + expf(-(xz + hz)));
  float nn = tanhf(xn + r * hn);
  float hold = hrow[col];
  float hnew = (1.f - z) * nn + z * hold;
  h_out[m * H_ + col] = hnew;
  HA[xrow + col] = hnew;
}

// ---------------- fused attention: dp GEMM + scores + softmax + context -----
// one block per batch row b; 256 threads.

__global__ __launch_bounds__(256) void k_attend(
    const float* __restrict__ h_src, const float* __restrict__ enc,
    const float* __restrict__ enc_proj, const int* __restrict__ inp,
    const float* __restrict__ Wdec, const float* __restrict__ bdec,
    const float* __restrict__ v, const float* __restrict__ vb,
    float* __restrict__ a_out, float* __restrict__ HA, int step) {
  __shared__ float hq[512];
  __shared__ float dp[512];
  __shared__ float vv[512];
  __shared__ float part[256];
  __shared__ float sc[128];
  __shared__ float red[128];
  const int b = blockIdx.x, tid = threadIdx.x;

  hq[tid] = h_src[b * H_ + tid];
  hq[tid + 256] = h_src[b * H_ + 256 + tid];
  vv[tid] = v[tid];
  vv[tid + 256] = v[tid + 256];
  __syncthreads();

  // dp = h @ Wdec^T + bdec
#pragma unroll
  for (int jj = 0; jj < 2; ++jj) {
    int j = tid + jj * 256;
    const float4* w4 = (const float4*)(Wdec + (size_t)j * H_);
    float acc = 0.f;
#pragma unroll 4
    for (int k4 = 0; k4 < H_ / 4; ++k4) {
      float4 w = w4[k4];
      float4 h4 = *(const float4*)&hq[k4 * 4];
      acc = fmaf(h4.x, w.x, fmaf(h4.y, w.y, fmaf(h4.z, w.z, fmaf(h4.w, w.w, acc))));
    }
    dp[j] = acc + bdec[j];
  }
  __syncthreads();

  // scores: s[t] = sum_a v[a]*tanh(enc_proj[b,t,a] + dp[a])
  {
    int t = tid & 127, half = tid >> 7;
    const float* ep = enc_proj + ((size_t)b * TI_ + t) * A_ + half * 256;
    const float* dph = dp + half * 256;
    const float* vh = vv + half * 256;
    float p = 0.f;
    for (int a = 0; a < 256; ++a) p = fmaf(vh[a], tanhf(ep[a] + dph[a]), p);
    part[tid] = p;
  }
  __syncthreads();
  if (tid < 128) {
    float s = part[tid] + part[tid + 128] + vb[0];
    if (inp[b * TI_ + tid] == 0) s = -INFINITY;
    sc[tid] = s;
    red[tid] = s;
  }
  __syncthreads();
  for (int o = 64; o > 0; o >>= 1) {
    if (tid < o) red[tid] = fmaxf(red[tid], red[tid + o]);
    __syncthreads();
  }
  float mx = red[0];
  __syncthreads();
  if (tid < 128) {
    float e = expf(sc[tid] - mx);
    sc[tid] = e;
    red[tid] = e;
  }
  __syncthreads();
  for (int o = 64; o > 0; o >>= 1) {
    if (tid < o) red[tid] += red[tid + o];
    __syncthreads();
  }
  float inv = 1.f / red[0];
  __syncthreads();

  // context: a[d] = sum_t pr[t]*enc[b,t,d]
  float4 acc = make_float4(0.f, 0.f, 0.f, 0.f);
  const float4* e4p = (const float4*)(enc + (size_t)b * TI_ * D2H_) + tid;
#pragma unroll 4
  for (int t2 = 0; t2 < TI_; ++t2) {
    float pr = sc[t2] * inv;
    float4 ev = e4p[(size_t)t2 * (D2H_ / 4)];
    acc.x = fmaf(pr, ev.x, acc.x);
    acc.y = fmaf(pr, ev.y, acc.y);
    acc.z = fmaf(pr, ev.z, acc.z);
    acc.w = fmaf(pr, ev.w, acc.w);
  }
  *(float4*)(a_out + (size_t)b * D2H_ + tid * 4) = acc;
  if (step >= 0)
    *(float4*)(HA + ((size_t)step * B_ + b) * G3_ + H_ + tid * 4) = acc;
}

// ---------------- lengths + last + dec0 --------------------------------------

__global__ __launch_bounds__(256) void k_dec0(
    const int* __restrict__ inp, const float* __restrict__ enc,
    const float* __restrict__ Wst, const float* __restrict__ bst,
    float* __restrict__ h0) {
  __shared__ float last[1024];
  __shared__ int redi[128];
  __shared__ int slen;
  const int b = blockIdx.x, tid = threadIdx.x;
  if (tid < 128) redi[tid] = (inp[b * TI_ + tid] != 0) ? 1 : 0;
  __syncthreads();
  for (int o = 64; o > 0; o >>= 1) {
    if (tid < o) redi[tid] += redi[tid + o];
    __syncthreads();
  }
  if (tid == 0) slen = min(redi[0], TI_ - 1);
  __syncthreads();
  int len = slen;
#pragma unroll
  for (int i = 0; i < 4; ++i)
    last[tid + i * 256] = enc[((size_t)b * TI_ + len) * D2H_ + tid + i * 256];
  __syncthreads();
#pragma unroll
  for (int jj = 0; jj < 2; ++jj) {
    int j = tid + jj * 256;
    const float4* w4 = (const float4*)(Wst + (size_t)j * D2H_);
    float acc = 0.f;
#pragma unroll 4
    for (int k4 = 0; k4 < D2H_ / 4; ++k4) {
      float4 w = w4[k4];
      float4 l4 = *(const float4*)&last[k4 * 4];
      acc = fmaf(l4.x, w.x, fmaf(l4.y, w.y, fmaf(l4.z, w.z, fmaf(l4.w, w.w, acc))));
    }
    h0[b * H_ + j] = acc + bst[j];
  }
}

// ---------------- launch ------------------------------------------------------

extern "C" void kernel_launch(void* const* d_in, const int* in_sizes, int n_in,
                              void* d_out, int out_size, void* d_ws, size_t ws_size,
                              hipStream_t stream) {
  const int*   inp     = (const int*)d_in[0];
  const int*   outi    = (const int*)d_in[1];
  const float* emb_inp = (const float*)d_in[2];
  const float* emb_out = (const float*)d_in[3];
  const float* eWih_f  = (const float*)d_in[4];
  const float* eWhh_f  = (const float*)d_in[5];
  const float* ebih_f  = (const float*)d_in[6];
  const float* ebhh_f  = (const float*)d_in[7];
  const float* eWih_b  = (const float*)d_in[8];
  const float* eWhh_b  = (const float*)d_in[9];
  const float* ebih_b  = (const float*)d_in[10];
  const float* ebhh_b  = (const float*)d_in[11];
  const float* dsW     = (const float*)d_in[12];
  const float* dsb     = (const float*)d_in[13];
  const float* dWih    = (const float*)d_in[14];
  const float* dWhh    = (const float*)d_in[15];
  const float* dbih    = (const float*)d_in[16];
  const float* dbhh    = (const float*)d_in[17];
  const float* aWenc   = (const float*)d_in[18];
  const float* abenc   = (const float*)d_in[19];
  const float* aWdec   = (const float*)d_in[20];
  const float* abdec   = (const float*)d_in[21];
  const float* av      = (const float*)d_in[22];
  const float* avb     = (const float*)d_in[23];
  const float* lW      = (const float*)d_in[24];
  const float* lb      = (const float*)d_in[25];
  float* dout = (float*)d_out;

  float* ws = (float*)d_ws;
  size_t off = 0;
  auto alloc = [&](size_t n) { float* p = ws + off; off += n; return p; };
  float* x    = alloc((size_t)B_ * TI_ * E_);       // 1.05M
  float* xp_f = alloc((size_t)B_ * TI_ * G3_);      // 6.3M
  float* xp_b = alloc((size_t)B_ * TI_ * G3_);      // 6.3M
  float* enc  = alloc((size_t)B_ * TI_ * D2H_);     // 4.2M
  float* encp = alloc((size_t)B_ * TI_ * A_);       // 2.1M
  float* xe   = alloc((size_t)63 * B_ * E_);        // 0.52M
  float* XE   = alloc((size_t)63 * B_ * G3_);       // 3.1M
  float* HA   = alloc((size_t)63 * B_ * G3_);       // 3.1M
  float* hf0  = alloc(B_ * H_);
  float* hf1  = alloc(B_ * H_);
  float* hb0  = alloc(B_ * H_);
  float* hb1  = alloc(B_ * H_);
  float* hd0  = alloc(B_ * H_);
  float* hd1  = alloc(B_ * H_);
  float* adec = alloc(B_ * D2H_);

  // zero initial encoder states
  k_zero<<<(2 * B_ * H_ + 255) / 256, 256, 0, stream>>>(hf0, B_ * H_);
  k_zero<<<(2 * B_ * H_ + 255) / 256, 256, 0, stream>>>(hb0, B_ * H_);

  // embeddings + input projections
  k_gather_x<<<(B_ * TI_ * E_ / 4 + 255) / 256, 256, 0, stream>>>(inp, emb_inp, x);
  dim3 g1(G3_ / 128, (B_ * TI_) / 128);
  k_gemm128<0><<<g1, 256, 0, stream>>>(x, E_, eWih_f, E_, ebih_f, xp_f, B_ * TI_, G3_, E_);
  k_gemm128<0><<<g1, 256, 0, stream>>>(x, E_, eWih_b, E_, ebih_b, xp_b, B_ * TI_, G3_, E_);

  // encoder recurrence (both directions per launch, ping-pong h)
  float* hfb[2] = {hf0, hf1};
  float* hbb[2] = {hb0, hb1};
  for (int t = 0; t < TI_; ++t) {
    k_enc_step<<<128, 256, 0, stream>>>(hfb[t & 1], hfb[(t + 1) & 1],
                                        hbb[t & 1], hbb[(t + 1) & 1],
                                        xp_f, xp_b, eWhh_f, ebhh_f, eWhh_b, ebhh_b,
                                        enc, t);
  }

  // enc_proj
  dim3 g2(A_ / 128, (B_ * TI_) / 128);
  k_gemm128<0><<<g2, 256, 0, stream>>>(enc, D2H_, aWenc, D2H_, abenc, encp, B_ * TI_, A_, D2H_);

  // dec0 + a0
  k_dec0<<<B_, 256, 0, stream>>>(inp, enc, dsW, dsb, hd0);
  k_attend<<<B_, 256, 0, stream>>>(hd0, enc, encp, inp, aWdec, abdec, av, avb, adec, HA, -1);

  // decoder token embedding projection (includes dec_bih)
  k_gather_xe<<<(63 * B_ * E_ / 4 + 255) / 256, 256, 0, stream>>>(outi, emb_out, xe);
  dim3 g3(G3_ / 128, (63 * B_ + 127) / 128);
  k_gemm128<0><<<g3, 256, 0, stream>>>(xe, E_, dWih, E_ + D2H_, dbih, XE, 63 * B_, G3_, E_);

  // decoder recurrence
  float* hdb[2] = {hd0, hd1};
  for (int i = 0; i < 63; ++i) {
    k_dec_step<<<64, 256, 0, stream>>>(hdb[i & 1], hdb[(i + 1) & 1], adec, XE,
                                       dWih, dWhh, dbhh, HA, i);
    k_attend<<<B_, 256, 0, stream>>>(hdb[(i + 1) & 1], enc, encp, inp,
                                     aWdec, abdec, av, avb, adec, HA, i);
  }

  // batched logits GEMM straight into d_out (rows 1..63 per batch)
  dim3 g4(VO_ / 128, (63 * B_ + 127) / 128);
  k_gemm128<1><<<g4, 256, 0, stream>>>(HA, G3_, lW, G3_, lb, dout, 63 * B_, VO_, G3_);

  // first token row: log(one_hot(BOS) + 1e-9)
  k_first<<<(B_ * VO_ + 255) / 256, 256, 0, stream>>>(dout);
}

// Round 2
// 10887.966 us; speedup vs baseline: 1.2992x; 1.2992x over previous
//
#include <hip/hip_runtime.h>
#include <math.h>
#include <stdint.h>

#define B_   32
#define TI_  128
#define TO_  64
#define E_   256
#define H_   512
#define A_   512
#define VO_  32000
#define G3_  1536   // 3H
#define D2H_ 1024   // 2H

using short8 = __attribute__((ext_vector_type(8))) short;
using f32x4  = __attribute__((ext_vector_type(4))) float;

__device__ __forceinline__ unsigned short f2bf(float x) {
  uint32_t u = __builtin_bit_cast(uint32_t, x);
  uint32_t r = (u + 0x7fffu + ((u >> 16) & 1u)) >> 16;
  return (unsigned short)r;
}

// ---------------- small utility kernels ----------------

__global__ __launch_bounds__(256) void k_zero(float* __restrict__ p, int n) {
  int i = blockIdx.x * 256 + threadIdx.x;
  if (i < n) p[i] = 0.f;
}

__global__ __launch_bounds__(256) void k_zero_u16(unsigned short* __restrict__ p, int n) {
  int i = blockIdx.x * 256 + threadIdx.x;
  if (i < n) p[i] = 0;
}

// f32 -> bf16, 8 elements per thread
__global__ __launch_bounds__(256) void k_cvt_bf16(const float* __restrict__ in,
                                                  unsigned short* __restrict__ out, int n8) {
  int i = blockIdx.x * 256 + threadIdx.x;
  if (i >= n8) return;
  float4 a = ((const float4*)in)[2 * i];
  float4 b = ((const float4*)in)[2 * i + 1];
  ushort4 lo = make_ushort4(f2bf(a.x), f2bf(a.y), f2bf(a.z), f2bf(a.w));
  ushort4 hi = make_ushort4(f2bf(b.x), f2bf(b.y), f2bf(b.z), f2bf(b.w));
  ((ushort4*)out)[2 * i] = lo;
  ((ushort4*)out)[2 * i + 1] = hi;
}

__global__ __launch_bounds__(256) void k_gather_x(const int* __restrict__ inp,
                                                  const float* __restrict__ emb,
                                                  float* __restrict__ x) {
  int idx = blockIdx.x * 256 + threadIdx.x;      // float4 index
  int total = B_ * TI_ * E_ / 4;
  if (idx >= total) return;
  int row = idx / (E_ / 4);
  int e4  = idx % (E_ / 4);
  int tok = inp[row];
  ((float4*)x)[idx] = ((const float4*)emb)[(size_t)tok * (E_ / 4) + e4];
}

__global__ __launch_bounds__(256) void k_gather_xe(const int* __restrict__ outidx,
                                                   const float* __restrict__ emb,
                                                   float* __restrict__ xe) {
  int idx = blockIdx.x * 256 + threadIdx.x;
  int total = 63 * B_ * E_ / 4;
  if (idx >= total) return;
  int row = idx / (E_ / 4);      // = i*32 + b
  int e4  = idx % (E_ / 4);
  int i = row / B_, b = row % B_;
  int tok = outidx[b * TO_ + i];
  ((float4*)xe)[idx] = ((const float4*)emb)[(size_t)tok * (E_ / 4) + e4];
}

__global__ __launch_bounds__(256) void k_first(float* __restrict__ dout) {
  int idx = blockIdx.x * 256 + threadIdx.x;
  if (idx >= B_ * VO_) return;
  int b = idx / VO_, v = idx % VO_;
  dout[(size_t)b * TO_ * VO_ + v] = (v == 1) ? 0.f : -20.72326583694641f;
}

// ---------------- generic f32 GEMM: C[M,N] = A[M,lda-K] @ W[N,ldw]^T + bias ----

__global__ __launch_bounds__(256) void k_gemm128(
    const float* __restrict__ A, int lda,
    const float* __restrict__ W, int ldw,
    const float* __restrict__ bias,
    float* __restrict__ C, int M, int N, int K) {
  __shared__ float As[32][132];
  __shared__ float Bs[32][132];
  const int tid = threadIdx.x;
  const int m0 = blockIdx.y * 128, n0 = blockIdx.x * 128;
  const int tx = tid & 15, ty = tid >> 4;
  float acc[8][8];
#pragma unroll
  for (int i = 0; i < 8; ++i)
#pragma unroll
    for (int j = 0; j < 8; ++j) acc[i][j] = 0.f;

  for (int k0 = 0; k0 < K; k0 += 32) {
#pragma unroll
    for (int i = 0; i < 16; ++i) {
      int idx = tid + i * 256;
      int kk = idx & 31, mm = idx >> 5;
      int m = m0 + mm;
      As[kk][mm] = (m < M) ? A[(size_t)m * lda + k0 + kk] : 0.f;
      Bs[kk][mm] = W[(size_t)(n0 + mm) * ldw + k0 + kk];
    }
    __syncthreads();
#pragma unroll
    for (int kk = 0; kk < 32; ++kk) {
      float4 a0 = *(const float4*)&As[kk][ty * 8];
      float4 a1 = *(const float4*)&As[kk][ty * 8 + 4];
      float4 b0 = *(const float4*)&Bs[kk][tx * 8];
      float4 b1 = *(const float4*)&Bs[kk][tx * 8 + 4];
      float av[8] = {a0.x, a0.y, a0.z, a0.w, a1.x, a1.y, a1.z, a1.w};
      float bv[8] = {b0.x, b0.y, b0.z, b0.w, b1.x, b1.y, b1.z, b1.w};
#pragma unroll
      for (int i = 0; i < 8; ++i)
#pragma unroll
        for (int j = 0; j < 8; ++j) acc[i][j] = fmaf(av[i], bv[j], acc[i][j]);
    }
    __syncthreads();
  }

#pragma unroll
  for (int i = 0; i < 8; ++i) {
    int m = m0 + ty * 8 + i;
    if (m >= M) continue;
#pragma unroll
    for (int j = 0; j < 8; ++j) {
      int n = n0 + tx * 8 + j;
      C[(size_t)m * N + n] = acc[i][j] + bias[n];
    }
  }
}

// ---------------- bf16 MFMA logits GEMM (m97 structure) ----------------------
// A: [2048][1536] bf16 (rows 0..2015 valid), Bt: [32000][1536] bf16.
// out[((m&31)*TO + (m>>5) + 1)*VO + n] = sum_k A[m][k]*Bt[n][k] + bias[n]
// grid (250, 16), 256 threads (4 waves, each wave owns 64x64 of the 128x128 tile).

__global__ __launch_bounds__(256) void k_logits_mfma(
    const unsigned short* __restrict__ A,
    const unsigned short* __restrict__ Bt,
    const float* __restrict__ bias,
    float* __restrict__ out) {
  __shared__ alignas(16) unsigned short As[128 * 32];
  __shared__ alignas(16) unsigned short Bs[128 * 32];
  const int tid = threadIdx.x;
  const int wave = tid >> 6, lane = tid & 63;
  const int m0 = blockIdx.y * 128, n0 = blockIdx.x * 128;
  const int wr = wave >> 1, wc = wave & 1;
  const int K = G3_;

  f32x4 acc[4][4];
#pragma unroll
  for (int i = 0; i < 4; ++i)
#pragma unroll
    for (int j = 0; j < 4; ++j) acc[i][j] = (f32x4){0.f, 0.f, 0.f, 0.f};

  const int srow = tid >> 2;            // 0..63, row within 64-row round
  const int sbyte = (tid & 3) * 16;     // byte within 64B k-slice
  const int fr = lane & 15;             // fragment row/col
  const int fkb = (lane >> 4) * 16;     // byte offset along K within tile row

  for (int k0 = 0; k0 < K; k0 += 32) {
#pragma unroll
    for (int rd = 0; rd < 2; ++rd) {
      int row = rd * 64 + srow;
      const char* ga = (const char*)(A + (size_t)(m0 + row) * K + k0) + sbyte;
      const char* gb = (const char*)(Bt + (size_t)(n0 + row) * K + k0) + sbyte;
      __builtin_amdgcn_global_load_lds(
          (const __attribute__((address_space(1))) uint32_t*)ga,
          (__attribute__((address_space(3))) uint32_t*)((char*)As + rd * 4096 + wave * 1024),
          16, 0, 0);
      __builtin_amdgcn_global_load_lds(
          (const __attribute__((address_space(1))) uint32_t*)gb,
          (__attribute__((address_space(3))) uint32_t*)((char*)Bs + rd * 4096 + wave * 1024),
          16, 0, 0);
    }
    __syncthreads();

    short8 af[4], bf[4];
#pragma unroll
    for (int i = 0; i < 4; ++i) {
      int ar = wr * 64 + i * 16 + fr;
      int bc = wc * 64 + i * 16 + fr;
      af[i] = *(const short8*)((const char*)As + ar * 64 + fkb);
      bf[i] = *(const short8*)((const char*)Bs + bc * 64 + fkb);
    }
#pragma unroll
    for (int i = 0; i < 4; ++i)
#pragma unroll
      for (int j = 0; j < 4; ++j)
        acc[i][j] = __builtin_amdgcn_mfma_f32_16x16x32_bf16(af[i], bf[j], acc[i][j], 0, 0, 0);
    __syncthreads();
  }

  const int crow = (lane >> 4) * 4, ccol = lane & 15;
#pragma unroll
  for (int i = 0; i < 4; ++i) {
#pragma unroll
    for (int r = 0; r < 4; ++r) {
      int m = m0 + wr * 64 + i * 16 + crow + r;
      if (m >= 63 * B_) continue;
      int b = m & 31, st = m >> 5;
      float* orow = out + ((size_t)b * TO_ + st + 1) * VO_;
#pragma unroll
      for (int j = 0; j < 4; ++j) {
        int n = n0 + wc * 64 + j * 16 + ccol;
        orow[n] = acc[i][j][r] + bias[n];
      }
    }
  }
}

// ---------------- encoder step (both directions, fused GEMM+gates) ----------

__global__ __launch_bounds__(256) void k_enc_step(
    const float* __restrict__ hf_in, float* __restrict__ hf_out,
    const float* __restrict__ hb_in, float* __restrict__ hb_out,
    const float* __restrict__ xp_f, const float* __restrict__ xp_b,
    const float* __restrict__ Whh_f, const float* __restrict__ bhh_f,
    const float* __restrict__ Whh_b, const float* __restrict__ bhh_b,
    float* __restrict__ enc, int t) {
  __shared__ float hs[32 * 516];
  const int bid = blockIdx.x;
  const int dir = bid >> 6;
  const int slice = bid & 63;
  const float* h_in  = dir ? hb_in : hf_in;
  float*       h_out = dir ? hb_out : hf_out;
  const float* xp    = dir ? xp_b : xp_f;
  const float* Whh   = dir ? Whh_b : Whh_f;
  const float* bhh   = dir ? bhh_b : bhh_f;
  const int tt = dir ? (TI_ - 1 - t) : t;
  const int tid = threadIdx.x;

#pragma unroll
  for (int i = 0; i < 16; ++i) {
    int idx4 = tid + i * 256;
    int flat = idx4 * 4;
    int mm = flat >> 9, kk = flat & 511;
    *(float4*)&hs[mm * 516 + kk] = *(const float4*)(h_in + (size_t)mm * H_ + kk);
  }
  __syncthreads();

  const int m = tid & 31, c = tid >> 5;
  const int col = slice * 8 + c;
  const float* hrow = hs + m * 516;
  const float4* wr = (const float4*)(Whh + (size_t)col * H_);
  const float4* wz = (const float4*)(Whh + (size_t)(H_ + col) * H_);
  const float4* wn = (const float4*)(Whh + (size_t)(2 * H_ + col) * H_);
  float accr = 0.f, accz = 0.f, accn = 0.f;
#pragma unroll 4
  for (int k4 = 0; k4 < H_ / 4; ++k4) {
    float4 h4 = *(const float4*)(hrow + k4 * 4);
    float4 r = wr[k4], z = wz[k4], n = wn[k4];
    accr = fmaf(h4.x, r.x, fmaf(h4.y, r.y, fmaf(h4.z, r.z, fmaf(h4.w, r.w, accr))));
    accz = fmaf(h4.x, z.x, fmaf(h4.y, z.y, fmaf(h4.z, z.z, fmaf(h4.w, z.w, accz))));
    accn = fmaf(h4.x, n.x, fmaf(h4.y, n.y, fmaf(h4.z, n.z, fmaf(h4.w, n.w, accn))));
  }
  size_t xoff = ((size_t)m * TI_ + tt) * G3_ + col;
  float xr = xp[xoff], xz = xp[xoff + 512], xn = xp[xoff + 1024];
  float hr = accr + bhh[col];
  float hz = accz + bhh[512 + col];
  float hn = accn + bhh[1024 + col];
  float r = 1.f / (1.f + expf(-(xr + hr)));
  float z = 1.f / (1.f + expf(-(xz + hz)));
  float nn = tanhf(xn + r * hn);
  float hold = hrow[col];
  float hnew = (1.f - z) * nn + z * hold;
  h_out[m * H_ + col] = hnew;
  enc[((size_t)m * TI_ + tt) * D2H_ + dir * H_ + col] = hnew;
}

// ---------------- decoder recurrence step ------------------------------------
// HA is bf16 now: writes h_new as bf16 into HA[(step*B+m)*G3 + col].

__global__ __launch_bounds__(256) void k_dec_step(
    const float* __restrict__ h_in, float* __restrict__ h_out,
    const float* __restrict__ a_in, const float* __restrict__ XE,
    const float* __restrict__ Wih, const float* __restrict__ Whh,
    const float* __restrict__ bhh,
    unsigned short* __restrict__ HA, int step) {
  __shared__ float buf[32 * 516];
  const int tid = threadIdx.x;
  const int m = tid & 31, c = tid >> 5;
  const int col = blockIdx.x * 8 + c;
  const float* hrow = buf + m * 516;
  float axr = 0.f, axz = 0.f, axn = 0.f, ahr = 0.f, ahz = 0.f, ahn = 0.f;

#pragma unroll
  for (int i = 0; i < 16; ++i) {
    int idx4 = tid + i * 256;
    int flat = idx4 * 4;
    int mm = flat >> 9, kk = flat & 511;
    *(float4*)&buf[mm * 516 + kk] = *(const float4*)(a_in + (size_t)mm * D2H_ + kk);
  }
  __syncthreads();
  {
    const float4* wr = (const float4*)(Wih + (size_t)col * 1280 + 256);
    const float4* wz = (const float4*)(Wih + (size_t)(512 + col) * 1280 + 256);
    const float4* wn = (const float4*)(Wih + (size_t)(1024 + col) * 1280 + 256);
#pragma unroll 4
    for (int k4 = 0; k4 < 128; ++k4) {
      float4 h4 = *(const float4*)(hrow + k4 * 4);
      float4 r = wr[k4], z = wz[k4], n = wn[k4];
      axr = fmaf(h4.x, r.x, fmaf(h4.y, r.y, fmaf(h4.z, r.z, fmaf(h4.w, r.w, axr))));
      axz = fmaf(h4.x, z.x, fmaf(h4.y, z.y, fmaf(h4.z, z.z, fmaf(h4.w, z.w, axz))));
      axn = fmaf(h4.x, n.x, fmaf(h4.y, n.y, fmaf(h4.z, n.z, fmaf(h4.w, n.w, axn))));
    }
  }
  __syncthreads();

#pragma unroll
  for (int i = 0; i < 16; ++i) {
    int idx4 = tid + i * 256;
    int flat = idx4 * 4;
    int mm = flat >> 9, kk = flat & 511;
    *(float4*)&buf[mm * 516 + kk] = *(const float4*)(a_in + (size_t)mm * D2H_ + 512 + kk);
  }
  __syncthreads();
  {
    const float4* wr = (const float4*)(Wih + (size_t)col * 1280 + 768);
    const float4* wz = (const float4*)(Wih + (size_t)(512 + col) * 1280 + 768);
    const float4* wn = (const float4*)(Wih + (size_t)(1024 + col) * 1280 + 768);
#pragma unroll 4
    for (int k4 = 0; k4 < 128; ++k4) {
      float4 h4 = *(const float4*)(hrow + k4 * 4);
      float4 r = wr[k4], z = wz[k4], n = wn[k4];
      axr = fmaf(h4.x, r.x, fmaf(h4.y, r.y, fmaf(h4.z, r.z, fmaf(h4.w, r.w, axr))));
      axz = fmaf(h4.x, z.x, fmaf(h4.y, z.y, fmaf(h4.z, z.z, fmaf(h4.w, z.w, axz))));
      axn = fmaf(h4.x, n.x, fmaf(h4.y, n.y, fmaf(h4.z, n.z, fmaf(h4.w, n.w, axn))));
    }
  }
  __syncthreads();

#pragma unroll
  for (int i = 0; i < 16; ++i) {
    int idx4 = tid + i * 256;
    int flat = idx4 * 4;
    int mm = flat >> 9, kk = flat & 511;
    *(float4*)&buf[mm * 516 + kk] = *(const float4*)(h_in + (size_t)mm * H_ + kk);
  }
  __syncthreads();
  {
    const float4* wr = (const float4*)(Whh + (size_t)col * H_);
    const float4* wz = (const float4*)(Whh + (size_t)(512 + col) * H_);
    const float4* wn = (const float4*)(Whh + (size_t)(1024 + col) * H_);
#pragma unroll 4
    for (int k4 = 0; k4 < 128; ++k4) {
      float4 h4 = *(const float4*)(hrow + k4 * 4);
      float4 r = wr[k4], z = wz[k4], n = wn[k4];
      ahr = fmaf(h4.x, r.x, fmaf(h4.y, r.y, fmaf(h4.z, r.z, fmaf(h4.w, r.w, ahr))));
      ahz = fmaf(h4.x, z.x, fmaf(h4.y, z.z, fmaf(h4.z, z.z, fmaf(h4.w, z.w, ahz))));
      ahn = fmaf(h4.x, n.x, fmaf(h4.y, n.y, fmaf(h4.z, n.z, fmaf(h4.w, n.w, ahn))));
    }
  }

  size_t xrow = ((size_t)step * B_ + m) * G3_;
  float xr = XE[xrow + col] + axr;
  float xz = XE[xrow + 512 + col] + axz;
  float xn = XE[xrow + 1024 + col] + axn;
  float hr = ahr + bhh[col];
  float hz = ahz + bhh[512 + col];
  float hn = ahn + bhh[1024 + col];
  float r = 1.f / (1.f + expf(-(xr + hr)));
  float z = 1.f / (1.f + expf(-(xz + hz)));
  float nn = tanhf(xn + r * hn);
  float hold = hrow[col];
  float hnew = (1.f - z) * nn + z * hold;
  h_out[m * H_ + col] = hnew;
  HA[xrow + col] = f2bf(hnew);
}

// ---------------- fused attention --------------------------------------------

__global__ __launch_bounds__(256) void k_attend(
    const float* __restrict__ h_src, const float* __restrict__ enc,
    const float* __restrict__ enc_proj, const int* __restrict__ inp,
    const float* __restrict__ Wdec, const float* __restrict__ bdec,
    const float* __restrict__ v, const float* __restrict__ vb,
    float* __restrict__ a_out, unsigned short* __restrict__ HA, int step) {
  __shared__ float hq[512];
  __shared__ float dp[512];
  __shared__ float vv[512];
  __shared__ float part[256];
  __shared__ float sc[128];
  __shared__ float red[128];
  const int b = blockIdx.x, tid = threadIdx.x;

  hq[tid] = h_src[b * H_ + tid];
  hq[tid + 256] = h_src[b * H_ + 256 + tid];
  vv[tid] = v[tid];
  vv[tid + 256] = v[tid + 256];
  __syncthreads();

#pragma unroll
  for (int jj = 0; jj < 2; ++jj) {
    int j = tid + jj * 256;
    const float4* w4 = (const float4*)(Wdec + (size_t)j * H_);
    float acc = 0.f;
#pragma unroll 4
    for (int k4 = 0; k4 < H_ / 4; ++k4) {
      float4 w = w4[k4];
      float4 h4 = *(const float4*)&hq[k4 * 4];
      acc = fmaf(h4.x, w.x, fmaf(h4.y, w.y, fmaf(h4.z, w.z, fmaf(h4.w, w.w, acc))));
    }
    dp[j] = acc + bdec[j];
  }
  __syncthreads();

  {
    int t = tid & 127, half = tid >> 7;
    const float* ep = enc_proj + ((size_t)b * TI_ + t) * A_ + half * 256;
    const float* dph = dp + half * 256;
    const float* vh = vv + half * 256;
    float p = 0.f;
    for (int a = 0; a < 256; ++a) p = fmaf(vh[a], tanhf(ep[a] + dph[a]), p);
    part[tid] = p;
  }
  __syncthreads();
  if (tid < 128) {
    float s = part[tid] + part[tid + 128] + vb[0];
    if (inp[b * TI_ + tid] == 0) s = -INFINITY;
    sc[tid] = s;
    red[tid] = s;
  }
  __syncthreads();
  for (int o = 64; o > 0; o >>= 1) {
    if (tid < o) red[tid] = fmaxf(red[tid], red[tid + o]);
    __syncthreads();
  }
  float mx = red[0];
  __syncthreads();
  if (tid < 128) {
    float e = expf(sc[tid] - mx);
    sc[tid] = e;
    red[tid] = e;
  }
  __syncthreads();
  for (int o = 64; o > 0; o >>= 1) {
    if (tid < o) red[tid] += red[tid + o];
    __syncthreads();
  }
  float inv = 1.f / red[0];
  __syncthreads();

  float4 acc = make_float4(0.f, 0.f, 0.f, 0.f);
  const float4* e4p = (const float4*)(enc + (size_t)b * TI_ * D2H_) + tid;
#pragma unroll 4
  for (int t2 = 0; t2 < TI_; ++t2) {
    float pr = sc[t2] * inv;
    float4 ev = e4p[(size_t)t2 * (D2H_ / 4)];
    acc.x = fmaf(pr, ev.x, acc.x);
    acc.y = fmaf(pr, ev.y, acc.y);
    acc.z = fmaf(pr, ev.z, acc.z);
    acc.w = fmaf(pr, ev.w, acc.w);
  }
  *(float4*)(a_out + (size_t)b * D2H_ + tid * 4) = acc;
  if (step >= 0) {
    unsigned short* hp = HA + ((size_t)step * B_ + b) * G3_ + H_ + tid * 4;
    *(ushort4*)hp = make_ushort4(f2bf(acc.x), f2bf(acc.y), f2bf(acc.z), f2bf(acc.w));
  }
}

// ---------------- lengths + last + dec0 --------------------------------------

__global__ __launch_bounds__(256) void k_dec0(
    const int* __restrict__ inp, const float* __restrict__ enc,
    const float* __restrict__ Wst, const float* __restrict__ bst,
    float* __restrict__ h0) {
  __shared__ float last[1024];
  __shared__ int redi[128];
  __shared__ int slen;
  const int b = blockIdx.x, tid = threadIdx.x;
  if (tid < 128) redi[tid] = (inp[b * TI_ + tid] != 0) ? 1 : 0;
  __syncthreads();
  for (int o = 64; o > 0; o >>= 1) {
    if (tid < o) redi[tid] += redi[tid + o];
    __syncthreads();
  }
  if (tid == 0) slen = min(redi[0], TI_ - 1);
  __syncthreads();
  int len = slen;
#pragma unroll
  for (int i = 0; i < 4; ++i)
    last[tid + i * 256] = enc[((size_t)b * TI_ + len) * D2H_ + tid + i * 256];
  __syncthreads();
#pragma unroll
  for (int jj = 0; jj < 2; ++jj) {
    int j = tid + jj * 256;
    const float4* w4 = (const float4*)(Wst + (size_t)j * D2H_);
    float acc = 0.f;
#pragma unroll 4
    for (int k4 = 0; k4 < D2H_ / 4; ++k4) {
      float4 w = w4[k4];
      float4 l4 = *(const float4*)&last[k4 * 4];
      acc = fmaf(l4.x, w.x, fmaf(l4.y, w.y, fmaf(l4.z, w.z, fmaf(l4.w, w.w, acc))));
    }
    h0[b * H_ + j] = acc + bst[j];
  }
}

// ---------------- launch ------------------------------------------------------

extern "C" void kernel_launch(void* const* d_in, const int* in_sizes, int n_in,
                              void* d_out, int out_size, void* d_ws, size_t ws_size,
                              hipStream_t stream) {
  const int*   inp     = (const int*)d_in[0];
  const int*   outi    = (const int*)d_in[1];
  const float* emb_inp = (const float*)d_in[2];
  const float* emb_out = (const float*)d_in[3];
  const float* eWih_f  = (const float*)d_in[4];
  const float* eWhh_f  = (const float*)d_in[5];
  const float* ebih_f  = (const float*)d_in[6];
  const float* ebhh_f  = (const float*)d_in[7];
  const float* eWih_b  = (const float*)d_in[8];
  const float* eWhh_b  = (const float*)d_in[9];
  const float* ebih_b  = (const float*)d_in[10];
  const float* ebhh_b  = (const float*)d_in[11];
  const float* dsW     = (const float*)d_in[12];
  const float* dsb     = (const float*)d_in[13];
  const float* dWih    = (const float*)d_in[14];
  const float* dWhh    = (const float*)d_in[15];
  const float* dbih    = (const float*)d_in[16];
  const float* dbhh    = (const float*)d_in[17];
  const float* aWenc   = (const float*)d_in[18];
  const float* abenc   = (const float*)d_in[19];
  const float* aWdec   = (const float*)d_in[20];
  const float* abdec   = (const float*)d_in[21];
  const float* av      = (const float*)d_in[22];
  const float* avb     = (const float*)d_in[23];
  const float* lW      = (const float*)d_in[24];
  const float* lb      = (const float*)d_in[25];
  float* dout = (float*)d_out;

  float* ws = (float*)d_ws;
  size_t off = 0;
  auto alloc = [&](size_t n) { float* p = ws + off; off += n; return p; };
  float* x    = alloc((size_t)B_ * TI_ * E_);
  float* xp_f = alloc((size_t)B_ * TI_ * G3_);
  float* xp_b = alloc((size_t)B_ * TI_ * G3_);
  float* enc  = alloc((size_t)B_ * TI_ * D2H_);
  float* encp = alloc((size_t)B_ * TI_ * A_);
  float* xe   = alloc((size_t)63 * B_ * E_);
  float* XE   = alloc((size_t)63 * B_ * G3_);
  unsigned short* HAb = (unsigned short*)alloc((size_t)2048 * G3_ / 2);   // bf16 [2048][1536]
  unsigned short* lWb = (unsigned short*)alloc((size_t)VO_ * G3_ / 2);    // bf16 [32000][1536]
  float* hf0  = alloc(B_ * H_);
  float* hf1  = alloc(B_ * H_);
  float* hb0  = alloc(B_ * H_);
  float* hb1  = alloc(B_ * H_);
  float* hd0  = alloc(B_ * H_);
  float* hd1  = alloc(B_ * H_);
  float* adec = alloc(B_ * D2H_);

  // zero initial encoder states + HA tail rows (2016..2047)
  k_zero<<<(2 * B_ * H_ + 255) / 256, 256, 0, stream>>>(hf0, B_ * H_);
  k_zero<<<(2 * B_ * H_ + 255) / 256, 256, 0, stream>>>(hb0, B_ * H_);
  k_zero_u16<<<(32 * G3_) / 256, 256, 0, stream>>>(HAb + (size_t)2016 * G3_, 32 * G3_);

  // convert logits weights to bf16 (L3-resident thereafter)
  k_cvt_bf16<<<((VO_ * G3_ / 8) + 255) / 256, 256, 0, stream>>>(lW, lWb, VO_ * G3_ / 8);

  // embeddings + input projections
  k_gather_x<<<(B_ * TI_ * E_ / 4 + 255) / 256, 256, 0, stream>>>(inp, emb_inp, x);
  dim3 g1(G3_ / 128, (B_ * TI_) / 128);
  k_gemm128<<<g1, 256, 0, stream>>>(x, E_, eWih_f, E_, ebih_f, xp_f, B_ * TI_, G3_, E_);
  k_gemm128<<<g1, 256, 0, stream>>>(x, E_, eWih_b, E_, ebih_b, xp_b, B_ * TI_, G3_, E_);

  // encoder recurrence
  float* hfb[2] = {hf0, hf1};
  float* hbb[2] = {hb0, hb1};
  for (int t = 0; t < TI_; ++t) {
    k_enc_step<<<128, 256, 0, stream>>>(hfb[t & 1], hfb[(t + 1) & 1],
                                        hbb[t & 1], hbb[(t + 1) & 1],
                                        xp_f, xp_b, eWhh_f, ebhh_f, eWhh_b, ebhh_b,
                                        enc, t);
  }

  // enc_proj
  dim3 g2(A_ / 128, (B_ * TI_) / 128);
  k_gemm128<<<g2, 256, 0, stream>>>(enc, D2H_, aWenc, D2H_, abenc, encp, B_ * TI_, A_, D2H_);

  // dec0 + a0
  k_dec0<<<B_, 256, 0, stream>>>(inp, enc, dsW, dsb, hd0);
  k_attend<<<B_, 256, 0, stream>>>(hd0, enc, encp, inp, aWdec, abdec, av, avb, adec, HAb, -1);

  // decoder token embedding projection (includes dec_bih)
  k_gather_xe<<<(63 * B_ * E_ / 4 + 255) / 256, 256, 0, stream>>>(outi, emb_out, xe);
  dim3 g3(G3_ / 128, (63 * B_ + 127) / 128);
  k_gemm128<<<g3, 256, 0, stream>>>(xe, E_, dWih, E_ + D2H_, dbih, XE, 63 * B_, G3_, E_);

  // decoder recurrence
  float* hdb[2] = {hd0, hd1};
  for (int i = 0; i < 63; ++i) {
    k_dec_step<<<64, 256, 0, stream>>>(hdb[i & 1], hdb[(i + 1) & 1], adec, XE,
                                       dWih, dWhh, dbhh, HAb, i);
    k_attend<<<B_, 256, 0, stream>>>(hdb[(i + 1) & 1], enc, encp, inp,
                                     aWdec, abdec, av, avb, adec, HAb, i);
  }

  // batched bf16 MFMA logits GEMM straight into d_out
  dim3 g4(VO_ / 128, 16);
  k_logits_mfma<<<g4, 256, 0, stream>>>(HAb, lWb, lb, dout);

  // first token row: log(one_hot(BOS) + 1e-9)
  k_first<<<(B_ * VO_ + 255) / 256, 256, 0, stream>>>(dout);
}